// Round 2
// baseline (4983.860 us; speedup 1.0000x reference)
//
#include <hip/hip_runtime.h>

// MatchLSTM forward pipeline for MI355X.
// R1: match_k/enc_k restructured for latency: fused h-dependent phase
// (gates_pre + sc concurrently), XA/pp/XG prefetched one step ahead.

typedef _Float16 f16;
typedef f16 f16x2 __attribute__((ext_vector_type(2)));
typedef unsigned int u32;
typedef unsigned short u16;

constexpr int cLP = 400, cLQ = 50, cB = 32, cH = 150, cG = 600;

__device__ __forceinline__ float exp2_(float x){
#if __has_builtin(__builtin_amdgcn_exp2f)
  return __builtin_amdgcn_exp2f(x);
#else
  return exp2f(x);
#endif
}
__device__ __forceinline__ float rcp_(float x){
#if __has_builtin(__builtin_amdgcn_rcpf)
  return __builtin_amdgcn_rcpf(x);
#else
  return 1.0f / x;
#endif
}
__device__ __forceinline__ float sigm(float x){ return rcp_(1.f + exp2_(-1.44269504f * x)); }
__device__ __forceinline__ float tanh_(float x){ return 1.f - 2.f * rcp_(1.f + exp2_(2.88539008f * x)); }

union U2 { u32 u; f16x2 h; };

__device__ __forceinline__ float fdot2_(u32 a, u32 b, float c){
  U2 ua, ub; ua.u = a; ub.u = b;
#if __has_builtin(__builtin_amdgcn_fdot2)
  return __builtin_amdgcn_fdot2(ua.h, ub.h, c, false);
#else
  return c + (float)ua.h[0] * (float)ub.h[0] + (float)ua.h[1] * (float)ub.h[1];
#endif
}
__device__ __forceinline__ u32 pack2(float x, float y){
  U2 p; p.h[0] = (f16)x; p.h[1] = (f16)y; return p.u;
}
__device__ __forceinline__ float2 unp2(u32 v){
  U2 p; p.u = v; return make_float2((float)p.h[0], (float)p.h[1]);
}

// ---------------------------------------------------------------------------
// Generic f32 GEMM: C[M][N] = A[M][K] @ W[N][K]^T (+bias). Optional embedding
// gather for A rows. Optional f16 output. Tile 64x64, 4x4/thread, 256 thr.
// ---------------------------------------------------------------------------
__global__ __launch_bounds__(256)
void gemm_k(const float* __restrict__ A, const int* __restrict__ ids,
            const float* __restrict__ emb,
            const float* __restrict__ W, int ldw, const float* __restrict__ bias,
            float* __restrict__ Cf, f16* __restrict__ Ch,
            int M, int N, int K)
{
  __shared__ __align__(16) float As[16][68];
  __shared__ __align__(16) float Wt[16][68];
  __shared__ int sids[64];
  int tid = threadIdx.x;
  int n0 = blockIdx.x * 64;
  int m0 = blockIdx.y * 64;
  int tx = tid & 15, ty = tid >> 4;
  if (ids){ if (tid < 64) sids[tid] = ids[m0 + tid]; }
  __syncthreads();

  float acc[4][4] = {};
  int sm = tid >> 2;
  int kq = (tid & 3) << 2;
  const float* arow = ids ? (emb + (size_t)sids[sm] * K)
                          : (A   + (size_t)(m0 + sm) * K);
  const float* wrow = W + (size_t)(n0 + sm) * ldw;
  bool nok = (n0 + sm) < N;

  for (int k0 = 0; k0 < K; k0 += 16){
    #pragma unroll
    for (int p = 0; p < 4; p++){
      int kk = kq + p, k = k0 + kk;
      As[kk][sm] = (k < K) ? arow[k] : 0.f;
      Wt[kk][sm] = (nok && k < K) ? wrow[k] : 0.f;
    }
    __syncthreads();
    #pragma unroll
    for (int kk = 0; kk < 16; kk++){
      float4 av = *(const float4*)&As[kk][ty << 2];
      float4 wv = *(const float4*)&Wt[kk][tx << 2];
      float a[4] = {av.x, av.y, av.z, av.w};
      float w[4] = {wv.x, wv.y, wv.z, wv.w};
      #pragma unroll
      for (int i = 0; i < 4; i++)
        #pragma unroll
        for (int j = 0; j < 4; j++)
          acc[i][j] += a[i] * w[j];
    }
    __syncthreads();
  }
  float bj[4];
  #pragma unroll
  for (int j = 0; j < 4; j++){
    int n = n0 + (tx << 2) + j;
    bj[j] = (bias && n < N) ? bias[n] : 0.f;
  }
  #pragma unroll
  for (int i = 0; i < 4; i++){
    int m = m0 + (ty << 2) + i;
    #pragma unroll
    for (int j = 0; j < 4; j++){
      int n = n0 + (tx << 2) + j;
      if (n < N){
        size_t ci = (size_t)m * N + n;
        float v = acc[i][j] + bj[j];
        if (Ch) Ch[ci] = (f16)v; else Cf[ci] = v;
      }
    }
  }
}

// ---------------------------------------------------------------------------
// Encoder LSTM. 64 WGs: wg<32 -> passage b, else question b. 640 threads.
// XG row prefetched one step ahead (hides HBM latency under the step).
// ---------------------------------------------------------------------------
__global__ __launch_bounds__(640)
void enc_k(const float* __restrict__ XGp, const float* __restrict__ XGq,
           const float* __restrict__ Whh,
           const int* __restrict__ plens, const int* __restrict__ qlens,
           float* __restrict__ Hp, float* __restrict__ Hq)
{
  int wg = blockIdx.x;
  bool isq = wg >= cB;
  int b = wg & (cB - 1);
  const float* XG = isq ? XGq : XGp;
  float* Hout = isq ? Hq : Hp;
  int T   = isq ? cLQ : cLP;
  int len = (isq ? qlens : plens)[b];
  int tid = threadIdx.x;

  __shared__ float c[cH], gl[cG];
  __shared__ __align__(16) u32 h2s[80];

  u32 w2[76];
  if (tid < cG){
    const float* wr = Whh + (size_t)tid * cH;
    #pragma unroll
    for (int p = 0; p < 75; p++){
      float2 wv = *(const float2*)&wr[2 * p];
      w2[p] = pack2(wv.x, wv.y);
    }
    w2[75] = 0;
  }
  if (tid < cH) c[tid] = 0.f;
  if (tid < 80) h2s[tid] = 0;
  __syncthreads();

  float xgCur = 0.f;
  if (tid < cG) xgCur = XG[(size_t)b * cG + tid];   // t=0 row

  for (int t = 0; t < T; t++){
    // prefetch next step's x-gate row (consumed next iteration)
    int tn = (t + 1 < T) ? t + 1 : t;
    float xgN = 0.f;
    if (tid < cG) xgN = XG[((size_t)tn * cB + b) * cG + tid];

    if (tid < cG){
      float acc = xgCur;
      #pragma unroll
      for (int i = 0; i < 19; i++){
        uint4 hq = *(const uint4*)&h2s[4 * i];
        acc = fdot2_(hq.x, w2[4 * i + 0], acc);
        acc = fdot2_(hq.y, w2[4 * i + 1], acc);
        acc = fdot2_(hq.z, w2[4 * i + 2], acc);
        acc = fdot2_(hq.w, w2[4 * i + 3], acc);
      }
      gl[tid] = acc;
    }
    __syncthreads();
    if (tid < 75){
      float hv[2];
      #pragma unroll
      for (int z = 0; z < 2; z++){
        int u = 2 * tid + z;
        float ig = sigm(gl[u]);
        float fg = sigm(gl[cH + u]);
        float gg = tanh_(gl[2 * cH + u]);
        float og = sigm(gl[3 * cH + u]);
        float c2 = fg * c[u] + ig * gg;
        float hh = og * tanh_(c2);
        c[u] = c2;
        hv[z] = hh;
      }
      h2s[tid] = pack2(hv[0], hv[1]);      // unmasked h carries the recurrence
      float mk = (t < len) ? 1.f : 0.f;
      float2 st; st.x = hv[0] * mk; st.y = hv[1] * mk;
      *(float2*)&Hout[((size_t)t * cB + b) * cH + 2 * tid] = st;
    }
    __syncthreads();
    xgCur = xgN;
  }
}

// ---------------------------------------------------------------------------
// Match-LSTM, fwd + bwd. 64 WGs = dir(2) x batch(32), 640 threads.
// Per step (5 barrier-phases, critical-path-minimized):
//  A': gates_pre = b + h@Whh^T + mk*XA  (600 thr, Whh f16 in VGPRs)
//      CONCURRENTLY sc = pp + h@Wr^T    (same 600 thr, 1/4-column each,
//      4-lane shfl reduce; Wr^T f16 in LDS)   [both depend only on h_{t-1}]
//  B : attention logits (400 thr, aq/wa in regs, sc in LDS)
//  C : softmax(50) on wave 0 -> alpha (f16 pairs)
//  D': gl = gates_pre(reg) + mk*(alpha@QW)  (7 fdot2)
//  E : LSTM cell (75 thr)
// XA[t+1], pp[t+1] prefetched at the top of step t.
// ---------------------------------------------------------------------------
__global__ __launch_bounds__(640)
void match_k(const f16* __restrict__ XAf, const f16* __restrict__ XAb,
             const f16* __restrict__ QWf, const f16* __restrict__ QWb,
             const float* __restrict__ aq, const float* __restrict__ pp,
             const float* __restrict__ mfWhh, const float* __restrict__ mbWhh,
             const float* __restrict__ mfb, const float* __restrict__ mbb,
             const float* __restrict__ Wr, const float* __restrict__ wa,
             const int* __restrict__ plens, float* __restrict__ Hr)
{
  constexpr int NPAD = 154;
  int wg = blockIdx.x;
  int dir = wg >> 5;
  int b = wg & 31;
  const f16* XA = dir ? XAb : XAf;
  const f16* QW = dir ? QWb : QWf;
  const float* Whh = dir ? mbWhh : mfWhh;
  const float* bm  = dir ? mbb   : mfb;
  int len = plens[b];
  int tid = threadIdx.x;

  __shared__ u32 WrT2[76 * 150];        // [pair p][j], f16x2-packed Wr^T
  __shared__ float gl[cG];
  __shared__ float sc[NPAD];            // pp_t + h@Wr^T (padded zeros)
  __shared__ float c[cH];
  __shared__ __align__(16) u32 h2s[80];
  __shared__ float loge[64];
  __shared__ __align__(16) u32 alpha2[28];

  // one-time loads ----------------------------------------------------------
  u32 w2[76]; float bk = 0.f;
  if (tid < cG){
    const float* wr = Whh + (size_t)tid * cH;
    #pragma unroll
    for (int p = 0; p < 75; p++){
      float2 wv = *(const float2*)&wr[2 * p];
      w2[p] = pack2(wv.x, wv.y);
    }
    w2[75] = 0;
    bk = bm[tid];
  }
  u32 q2[28];
  if (tid < cG){
    const u16* QWu = (const u16*)QW;
    #pragma unroll
    for (int p = 0; p < 25; p++){
      size_t i0 = ((size_t)(2 * p) * cB + b) * cG + tid;
      size_t i1 = ((size_t)(2 * p + 1) * cB + b) * cG + tid;
      q2[p] = (u32)QWu[i0] | ((u32)QWu[i1] << 16);
    }
    q2[25] = 0; q2[26] = 0; q2[27] = 0;
  }
  u32 aqr[10];
  float waR0[10], waR1[10];
  if (tid < 400){
    int l = tid >> 3, j0 = (tid & 7) * 19;
    const float* ap = aq + ((size_t)l * cB + b) * cH;
    #pragma unroll
    for (int p = 0; p < 10; p++){
      int j = j0 + 2 * p;
      float a0 = (j     < cH) ? ap[j]     : 0.f;
      float a1 = (j + 1 < cH) ? ap[j + 1] : 0.f;
      aqr[p] = pack2(a0, a1);
      waR0[p] = (j < cH) ? wa[j] : 0.f;
      waR1[p] = (p == 9 || j + 1 >= cH) ? 0.f : wa[j + 1];
    }
  }
  for (int idx = tid; idx < 76 * 150; idx += 640){
    int p = idx / 150, k2 = idx % 150;
    WrT2[idx] = (p < 75) ? pack2(Wr[(size_t)k2 * cH + 2 * p],
                                 Wr[(size_t)k2 * cH + 2 * p + 1]) : 0u;
  }
  if (tid < cH) c[tid] = 0.f;
  if (tid < 80) h2s[tid] = 0;
  if (tid >= cH && tid < NPAD) sc[tid] = 0.f;
  __syncthreads();

  // prologue prefetch for step 0
  f16 xaCurH = (f16)0.f, xaNxtH = (f16)0.f;
  float ppCur = 0.f, ppNxt = 0.f;
  {
    int t0 = dir ? (cLP - 1) : 0;
    if (tid < cG) xaCurH = XA[((size_t)t0 * cB + b) * cG + tid];
    if (tid < cG && (tid & 3) == 0)
      ppCur = pp[((size_t)t0 * cB + b) * cH + (tid >> 2)];
  }

  for (int s = 0; s < cLP; s++){
    int tt = dir ? (cLP - 1 - s) : s;
    float mk = (tt < len) ? 1.f : 0.f;

    // prefetch step s+1 (fire-and-forget; consumed next iteration)
    {
      int sn = (s + 1 < cLP) ? s + 1 : s;
      int tn = dir ? (cLP - 1 - sn) : sn;
      if (tid < cG) xaNxtH = XA[((size_t)tn * cB + b) * cG + tid];
      if (tid < cG && (tid & 3) == 0)
        ppNxt = pp[((size_t)tn * cB + b) * cH + (tid >> 2)];
    }

    // A': gates_pre AND sc, both from h_{t-1}
    float gpre = 0.f;
    if (tid < cG){
      float acc = 0.f;
      #pragma unroll
      for (int i = 0; i < 19; i++){
        uint4 hq = *(const uint4*)&h2s[4 * i];
        acc = fdot2_(hq.x, w2[4 * i + 0], acc);
        acc = fdot2_(hq.y, w2[4 * i + 1], acc);
        acc = fdot2_(hq.z, w2[4 * i + 2], acc);
        acc = fdot2_(hq.w, w2[4 * i + 3], acc);
      }
      gpre = bk + acc + mk * (float)xaCurH;

      int j = tid >> 2, q = tid & 3;
      float as = 0.f;
      int p0 = q * 19;
      #pragma unroll
      for (int i = 0; i < 19; i++){
        int p = p0 + i;
        as = fdot2_(h2s[p], WrT2[p * 150 + j], as);
      }
      as += __shfl_xor(as, 1);
      as += __shfl_xor(as, 2);
      if (q == 0) sc[j] = as + ppCur;
    }
    __syncthreads();

    // B: attention logit partials; tanh = 1-2r, softmax drops constants.
    if (tid < 400){
      int j0 = (tid & 7) * 19;
      float part = 0.f;
      #pragma unroll
      for (int p = 0; p < 10; p++){
        int j = j0 + 2 * p;
        float2 av = unp2(aqr[p]);
        float x0 = av.x + sc[j];
        float x1 = av.y + sc[j + 1];
        float r0 = rcp_(1.f + exp2_(2.88539008f * x0));
        float r1 = rcp_(1.f + exp2_(2.88539008f * x1));
        part += waR0[p] * r0 + waR1[p] * r1;
      }
      part += __shfl_xor(part, 1);
      part += __shfl_xor(part, 2);
      part += __shfl_xor(part, 4);
      if ((tid & 7) == 0) loge[tid >> 3] = part;
    }
    __syncthreads();

    // C: softmax over 50 on wave 0, f16-packed alpha pairs
    if (tid < 64){
      float lg = (tid < cLQ) ? (-2.f * loge[tid]) : -1e30f;
      float mx = lg;
      #pragma unroll
      for (int off = 32; off; off >>= 1) mx = fmaxf(mx, __shfl_xor(mx, off));
      float e = (tid < cLQ) ? exp2_((lg - mx) * 1.44269504f) : 0.f;
      float sum = e;
      #pragma unroll
      for (int off = 32; off; off >>= 1) sum += __shfl_xor(sum, off);
      float al = e * rcp_(sum);
      float alhi = __shfl_down(al, 1);
      if (tid < cLQ && !(tid & 1)) alpha2[tid >> 1] = pack2(al, alhi);
      if (tid >= 25 && tid < 28) alpha2[tid] = 0;
    }
    __syncthreads();

    // D': gl = gates_pre + mk*(alpha@QW)
    if (tid < cG){
      float accq = 0.f;
      #pragma unroll
      for (int i = 0; i < 7; i++){
        uint4 a4 = *(const uint4*)&alpha2[4 * i];
        accq = fdot2_(a4.x, q2[4 * i + 0], accq);
        accq = fdot2_(a4.y, q2[4 * i + 1], accq);
        accq = fdot2_(a4.z, q2[4 * i + 2], accq);
        accq = fdot2_(a4.w, q2[4 * i + 3], accq);
      }
      gl[tid] = gpre + mk * accq;
    }
    __syncthreads();

    // E: LSTM cell; h2,c2 masked inside recurrence (ref semantics)
    if (tid < 75){
      float hv[2];
      #pragma unroll
      for (int z = 0; z < 2; z++){
        int u = 2 * tid + z;
        float ig = sigm(gl[u]);
        float fg = sigm(gl[cH + u]);
        float gg = tanh_(gl[2 * cH + u]);
        float og = sigm(gl[3 * cH + u]);
        float c2 = (fg * c[u] + ig * gg) * mk;
        float hh = og * tanh_(c2) * mk;
        c[u] = c2;
        hv[z] = hh;
      }
      h2s[tid] = pack2(hv[0], hv[1]);
      float2 st; st.x = hv[0]; st.y = hv[1];
      *(float2*)&Hr[((size_t)tt * cB + b) * (2 * cH) + dir * cH + 2 * tid] = st;
    }
    __syncthreads();

    xaCurH = xaNxtH;
    ppCur  = ppNxt;
  }
}

// ---------------------------------------------------------------------------
// Answer pointer: 32 WGs (one per batch), 2 sequential iterations.
// ---------------------------------------------------------------------------
__global__ __launch_bounds__(640)
void ptr_k(const float* __restrict__ am, const float* __restrict__ Hr,
           const float* __restrict__ Wa, const float* __restrict__ baa,
           const float* __restrict__ wb,
           const float* __restrict__ apWih, const float* __restrict__ apWhh,
             const float* __restrict__ apb, float* __restrict__ out)
{
  int b = blockIdx.x, tid = threadIdx.x;
  __shared__ float ha[cH], ca[cH], haWa[160], wbs[160];
  __shared__ float beta[cLP], wHr[2 * cH], gl[cG], red[20];
  if (tid < cH){ ha[tid] = 0.f; ca[tid] = 0.f; }
  if (tid < 160) wbs[tid] = (tid < cH) ? wb[tid] : 0.f;
  __syncthreads();

  for (int it = 0; it < 2; ++it){
    if (tid < cH){
      float acc = baa[tid];
      const float* wr = Wa + (size_t)tid * cH;
      for (int i = 0; i < cH; i++) acc += ha[i] * wr[i];
      haWa[tid] = acc;
    } else if (tid < 160) haWa[tid] = 0.f;
    __syncthreads();

    {
      int tt = tid >> 4;
      int jq = tid & 15;
      for (int t0 = 0; t0 < cLP; t0 += 40){
        int t = t0 + tt;
        float part = 0.f;
        const float* amr = am + ((size_t)t * cB + b) * cH;
        #pragma unroll
        for (int i = 0; i < 10; i++){
          int j = jq * 10 + i;
          if (j < cH){
            float F = tanh_(amr[j] + haWa[j]);
            part += wbs[j] * F;
          }
        }
        part += __shfl_xor(part, 1);
        part += __shfl_xor(part, 2);
        part += __shfl_xor(part, 4);
        part += __shfl_xor(part, 8);
        if (jq == 0) beta[t] = part;
      }
    }
    __syncthreads();

    float x = (tid < cLP) ? beta[tid] : -1e30f;
    float mx = x;
    #pragma unroll
    for (int off = 32; off; off >>= 1) mx = fmaxf(mx, __shfl_xor(mx, off));
    if ((tid & 63) == 0) red[tid >> 6] = mx;
    __syncthreads();
    if (tid == 0){
      float m2 = red[0];
      for (int w = 1; w < 10; w++) m2 = fmaxf(m2, red[w]);
      red[16] = m2;
    }
    __syncthreads();
    mx = red[16];
    float e = (tid < cLP) ? exp2_((x - mx) * 1.44269504f) : 0.f;
    float sm = e;
    #pragma unroll
    for (int off = 32; off; off >>= 1) sm += __shfl_xor(sm, off);
    if ((tid & 63) == 0) red[tid >> 6] = sm;
    __syncthreads();
    if (tid == 0){
      float s2 = 0.f;
      for (int w = 0; w < 10; w++) s2 += red[w];
      red[17] = s2;
    }
    __syncthreads();
    float bsum = red[17];
    if (tid < cLP){
      float bt = e * rcp_(bsum);
      beta[tid] = bt;
      out[(size_t)it * cLP * cB + (size_t)tid * cB + b] = bt;
    }
    __syncthreads();

    if (tid < 2 * cH){
      float acc = 0.f;
      for (int t = 0; t < cLP; t++)
        acc += beta[t] * Hr[((size_t)t * cB + b) * (2 * cH) + tid];
      wHr[tid] = acc;
    }
    __syncthreads();

    if (tid < cG){
      float acc = apb[tid];
      const float* r1 = apWih + (size_t)tid * (2 * cH);
      for (int i = 0; i < 2 * cH; i++) acc += wHr[i] * r1[i];
      const float* r2 = apWhh + (size_t)tid * cH;
      for (int i = 0; i < cH; i++) acc += ha[i] * r2[i];
      gl[tid] = acc;
    }
    __syncthreads();
    if (tid < cH){
      float ig = sigm(gl[tid]);
      float fg = sigm(gl[cH + tid]);
      float gg = tanh_(gl[2 * cH + tid]);
      float og = sigm(gl[3 * cH + tid]);
      float c2 = fg * ca[tid] + ig * gg;
      ca[tid] = c2;
      ha[tid] = og * tanh_(c2);
    }
    __syncthreads();
  }
}

// ---------------------------------------------------------------------------
extern "C" void kernel_launch(void* const* d_in, const int* in_sizes, int n_in,
                              void* d_out, int out_size, void* d_ws, size_t ws_size,
                              hipStream_t stream)
{
  (void)in_sizes; (void)n_in; (void)out_size; (void)ws_size;
  const int*   p_ids = (const int*)d_in[0];
  const int*   q_ids = (const int*)d_in[1];
  const int*   plens = (const int*)d_in[2];
  const int*   qlens = (const int*)d_in[3];
  const float* emb   = (const float*)d_in[4];
  const float* pWih  = (const float*)d_in[5];
  const float* pWhh  = (const float*)d_in[6];
  const float* pb    = (const float*)d_in[7];
  const float* Wq    = (const float*)d_in[8];
  const float* Wp    = (const float*)d_in[9];
  const float* bp    = (const float*)d_in[10];
  const float* Wr    = (const float*)d_in[11];
  const float* wa    = (const float*)d_in[12];
  const float* mfWih = (const float*)d_in[14];
  const float* mfWhh = (const float*)d_in[15];
  const float* mfb   = (const float*)d_in[16];
  const float* mbWih = (const float*)d_in[17];
  const float* mbWhh = (const float*)d_in[18];
  const float* mbb   = (const float*)d_in[19];
  const float* Vm    = (const float*)d_in[20];
  const float* Waa   = (const float*)d_in[21];
  const float* baa   = (const float*)d_in[22];
  const float* wb    = (const float*)d_in[23];
  const float* apWih = (const float*)d_in[25];
  const float* apWhh = (const float*)d_in[26];
  const float* apb   = (const float*)d_in[27];
  float* out = (float*)d_out;

  // workspace layout (floats); total 22,560,000 f = 90.24 MB
  float* ws  = (float*)d_ws;
  float* XGp = ws;                       // [400*32][600] f32 (later aliased XAf)
  float* XGq = ws + 7680000;             // [50*32][600]  f32 (later aliased QW)
  f16*   XAb = (f16*)(ws + 8640000);     // [400*32][600] f16
  float* Hp  = ws + 12480000;            // [400*32][150]
  float* Hq  = ws + 14400000;            // [50*32][150]
  float* aqb = ws + 14640000;            // [50*32][150]
  float* ppb = ws + 14880000;            // [400*32][150]
  float* Hr  = ws + 16800000;            // [400*32][300]
  float* am  = ws + 20640000;            // [400*32][150]
  f16*   XAf = (f16*)XGp;                // alias: XGp dead after enc_k
  f16*   QWf = (f16*)XGq;                // alias: XGq dead after enc_k
  f16*   QWb = QWf + (size_t)1600 * 600;

  dim3 blk(256);
  gemm_k<<<dim3(10,200), blk, 0, stream>>>(nullptr, p_ids, emb, pWih, 300, pb,
                                           XGp, nullptr, 12800, 600, 300);
  gemm_k<<<dim3(10, 25), blk, 0, stream>>>(nullptr, q_ids, emb, pWih, 300, pb,
                                           XGq, nullptr, 1600, 600, 300);
  enc_k<<<64, 640, 0, stream>>>(XGp, XGq, pWhh, plens, qlens, Hp, Hq);
  gemm_k<<<dim3(3,200), blk, 0, stream>>>(Hp, nullptr, nullptr, Wp, 150, bp,
                                          ppb, nullptr, 12800, 150, 150);
  gemm_k<<<dim3(3, 25), blk, 0, stream>>>(Hq, nullptr, nullptr, Wq, 150, nullptr,
                                          aqb, nullptr, 1600, 150, 150);
  gemm_k<<<dim3(10,200), blk, 0, stream>>>(Hp, nullptr, nullptr, mfWih, 300, nullptr,
                                           nullptr, XAf, 12800, 600, 150);
  gemm_k<<<dim3(10,200), blk, 0, stream>>>(Hp, nullptr, nullptr, mbWih, 300, nullptr,
                                           nullptr, XAb, 12800, 600, 150);
  gemm_k<<<dim3(10, 25), blk, 0, stream>>>(Hq, nullptr, nullptr, mfWih + 150, 300, nullptr,
                                           nullptr, QWf, 1600, 600, 150);
  gemm_k<<<dim3(10, 25), blk, 0, stream>>>(Hq, nullptr, nullptr, mbWih + 150, 300, nullptr,
                                           nullptr, QWb, 1600, 600, 150);
  match_k<<<64, 640, 0, stream>>>(XAf, XAb, QWf, QWb, aqb, ppb, mfWhh, mbWhh,
                                  mfb, mbb, Wr, wa, plens, Hr);
  gemm_k<<<dim3(3,200), blk, 0, stream>>>(Hr, nullptr, nullptr, Vm, 300, nullptr,
                                          am, nullptr, 12800, 150, 300);
  ptr_k<<<32, 640, 0, stream>>>(am, Hr, Waa, baa, wb, apWih, apWhh, apb, out);
}

// Round 3
// 3016.238 us; speedup vs baseline: 1.6523x; 1.6523x over previous
//
#include <hip/hip_runtime.h>

// MatchLSTM forward pipeline for MI355X.
// R2: kill register spills in the recurrent kernels. match_k keeps only
// w2[76]+q2[28] per-thread arrays (aq/wa moved to LDS), __launch_bounds__
// caps occupancy so they truly allocate; accumulator chains split 8-way.

typedef _Float16 f16;
typedef f16 f16x2 __attribute__((ext_vector_type(2)));
typedef unsigned int u32;
typedef unsigned short u16;

constexpr int cLP = 400, cLQ = 50, cB = 32, cH = 150, cG = 600;

__device__ __forceinline__ float exp2_(float x){
#if __has_builtin(__builtin_amdgcn_exp2f)
  return __builtin_amdgcn_exp2f(x);
#else
  return exp2f(x);
#endif
}
__device__ __forceinline__ float rcp_(float x){
#if __has_builtin(__builtin_amdgcn_rcpf)
  return __builtin_amdgcn_rcpf(x);
#else
  return 1.0f / x;
#endif
}
__device__ __forceinline__ float sigm(float x){ return rcp_(1.f + exp2_(-1.44269504f * x)); }
__device__ __forceinline__ float tanh_(float x){ return 1.f - 2.f * rcp_(1.f + exp2_(2.88539008f * x)); }

union U2 { u32 u; f16x2 h; };

__device__ __forceinline__ float fdot2_(u32 a, u32 b, float c){
  U2 ua, ub; ua.u = a; ub.u = b;
#if __has_builtin(__builtin_amdgcn_fdot2)
  return __builtin_amdgcn_fdot2(ua.h, ub.h, c, false);
#else
  return c + (float)ua.h[0] * (float)ub.h[0] + (float)ua.h[1] * (float)ub.h[1];
#endif
}
__device__ __forceinline__ u32 pack2(float x, float y){
  U2 p; p.h[0] = (f16)x; p.h[1] = (f16)y; return p.u;
}
__device__ __forceinline__ float2 unp2(u32 v){
  U2 p; p.u = v; return make_float2((float)p.h[0], (float)p.h[1]);
}

// ---------------------------------------------------------------------------
// Generic f32 GEMM: C[M][N] = A[M][K] @ W[N][K]^T (+bias). Optional embedding
// gather for A rows. Optional f16 output. Tile 64x64, 4x4/thread, 256 thr.
// ---------------------------------------------------------------------------
__global__ __launch_bounds__(256)
void gemm_k(const float* __restrict__ A, const int* __restrict__ ids,
            const float* __restrict__ emb,
            const float* __restrict__ W, int ldw, const float* __restrict__ bias,
            float* __restrict__ Cf, f16* __restrict__ Ch,
            int M, int N, int K)
{
  __shared__ __align__(16) float As[16][68];
  __shared__ __align__(16) float Wt[16][68];
  __shared__ int sids[64];
  int tid = threadIdx.x;
  int n0 = blockIdx.x * 64;
  int m0 = blockIdx.y * 64;
  int tx = tid & 15, ty = tid >> 4;
  if (ids){ if (tid < 64) sids[tid] = ids[m0 + tid]; }
  __syncthreads();

  float acc[4][4] = {};
  int sm = tid >> 2;
  int kq = (tid & 3) << 2;
  const float* arow = ids ? (emb + (size_t)sids[sm] * K)
                          : (A   + (size_t)(m0 + sm) * K);
  const float* wrow = W + (size_t)(n0 + sm) * ldw;
  bool nok = (n0 + sm) < N;

  for (int k0 = 0; k0 < K; k0 += 16){
    #pragma unroll
    for (int p = 0; p < 4; p++){
      int kk = kq + p, k = k0 + kk;
      As[kk][sm] = (k < K) ? arow[k] : 0.f;
      Wt[kk][sm] = (nok && k < K) ? wrow[k] : 0.f;
    }
    __syncthreads();
    #pragma unroll
    for (int kk = 0; kk < 16; kk++){
      float4 av = *(const float4*)&As[kk][ty << 2];
      float4 wv = *(const float4*)&Wt[kk][tx << 2];
      float a[4] = {av.x, av.y, av.z, av.w};
      float w[4] = {wv.x, wv.y, wv.z, wv.w};
      #pragma unroll
      for (int i = 0; i < 4; i++)
        #pragma unroll
        for (int j = 0; j < 4; j++)
          acc[i][j] += a[i] * w[j];
    }
    __syncthreads();
  }
  float bj[4];
  #pragma unroll
  for (int j = 0; j < 4; j++){
    int n = n0 + (tx << 2) + j;
    bj[j] = (bias && n < N) ? bias[n] : 0.f;
  }
  #pragma unroll
  for (int i = 0; i < 4; i++){
    int m = m0 + (ty << 2) + i;
    #pragma unroll
    for (int j = 0; j < 4; j++){
      int n = n0 + (tx << 2) + j;
      if (n < N){
        size_t ci = (size_t)m * N + n;
        float v = acc[i][j] + bj[j];
        if (Ch) Ch[ci] = (f16)v; else Cf[ci] = v;
      }
    }
  }
}

// ---------------------------------------------------------------------------
// Encoder LSTM. 64 WGs: wg<32 -> passage b, else question b. 640 threads.
// Whh rows f16-packed in VGPRs (76 u32/thread); launch bounds sized so they
// do NOT spill. 8 independent accumulator chains. XG prefetched 1 step ahead.
// ---------------------------------------------------------------------------
__global__ __launch_bounds__(640, 3)
void enc_k(const float* __restrict__ XGp, const float* __restrict__ XGq,
           const float* __restrict__ Whh,
           const int* __restrict__ plens, const int* __restrict__ qlens,
           float* __restrict__ Hp, float* __restrict__ Hq)
{
  int wg = blockIdx.x;
  bool isq = wg >= cB;
  int b = wg & (cB - 1);
  const float* XG = isq ? XGq : XGp;
  float* Hout = isq ? Hq : Hp;
  int T   = isq ? cLQ : cLP;
  int len = (isq ? qlens : plens)[b];
  int tid = threadIdx.x;

  __shared__ float c[cH], gl[cG];
  __shared__ __align__(16) u32 h2s[80];

  u32 w2[76];
  if (tid < cG){
    const float* wr = Whh + (size_t)tid * cH;
    #pragma unroll
    for (int p = 0; p < 75; p++){
      float2 wv = *(const float2*)&wr[2 * p];
      w2[p] = pack2(wv.x, wv.y);
    }
    w2[75] = 0;
  }
  if (tid < cH) c[tid] = 0.f;
  if (tid < 80) h2s[tid] = 0;
  __syncthreads();

  float xgCur = 0.f;
  if (tid < cG) xgCur = XG[(size_t)b * cG + tid];

  for (int t = 0; t < T; t++){
    int tn = (t + 1 < T) ? t + 1 : t;
    float xgN = 0.f;
    if (tid < cG) xgN = XG[((size_t)tn * cB + b) * cG + tid];

    if (tid < cG){
      float aA[4] = {}, aB[4] = {};
      #pragma unroll
      for (int i = 0; i < 19; i++){
        uint4 hq = *(const uint4*)&h2s[4 * i];
        aA[i & 3] = fdot2_(hq.x, w2[4 * i + 0], aA[i & 3]);
        aA[i & 3] = fdot2_(hq.y, w2[4 * i + 1], aA[i & 3]);
        aB[i & 3] = fdot2_(hq.z, w2[4 * i + 2], aB[i & 3]);
        aB[i & 3] = fdot2_(hq.w, w2[4 * i + 3], aB[i & 3]);
      }
      gl[tid] = xgCur + ((aA[0] + aA[1]) + (aA[2] + aA[3]))
                      + ((aB[0] + aB[1]) + (aB[2] + aB[3]));
    }
    __syncthreads();
    if (tid < 75){
      float hv[2];
      #pragma unroll
      for (int z = 0; z < 2; z++){
        int u = 2 * tid + z;
        float ig = sigm(gl[u]);
        float fg = sigm(gl[cH + u]);
        float gg = tanh_(gl[2 * cH + u]);
        float og = sigm(gl[3 * cH + u]);
        float c2 = fg * c[u] + ig * gg;
        float hh = og * tanh_(c2);
        c[u] = c2;
        hv[z] = hh;
      }
      h2s[tid] = pack2(hv[0], hv[1]);      // unmasked h carries the recurrence
      float mk = (t < len) ? 1.f : 0.f;
      float2 st; st.x = hv[0] * mk; st.y = hv[1] * mk;
      *(float2*)&Hout[((size_t)t * cB + b) * cH + 2 * tid] = st;
    }
    __syncthreads();
    xgCur = xgN;
  }
}

// ---------------------------------------------------------------------------
// Match-LSTM, fwd + bwd. 64 WGs = dir(2) x batch(32), 640 threads.
// R0 5-phase structure; per-thread arrays limited to w2[76]+q2[28] (fit in
// VGPRs under __launch_bounds__(640,3)); aq + wa live in LDS; XA/pp
// prefetched one step ahead; 8-way split accumulator chains.
// ---------------------------------------------------------------------------
__global__ __launch_bounds__(640, 3)
void match_k(const f16* __restrict__ XAf, const f16* __restrict__ XAb,
             const f16* __restrict__ QWf, const f16* __restrict__ QWb,
             const float* __restrict__ aq, const float* __restrict__ pp,
             const float* __restrict__ mfWhh, const float* __restrict__ mbWhh,
             const float* __restrict__ mfb, const float* __restrict__ mbb,
             const float* __restrict__ Wr, const float* __restrict__ wa,
             const int* __restrict__ plens, float* __restrict__ Hr)
{
  constexpr int NPAD = 160;   // sc/waS padded with zeros so phase B needs no masks
  constexpr int AQS  = 81;    // aq2 row stride (u32 pairs), odd to spread banks
  int wg = blockIdx.x;
  int dir = wg >> 5;
  int b = wg & 31;
  const f16* XA = dir ? XAb : XAf;
  const f16* QW = dir ? QWb : QWf;
  const float* Whh = dir ? mbWhh : mfWhh;
  const float* bm  = dir ? mbb   : mfb;
  int len = plens[b];
  int tid = threadIdx.x;

  __shared__ u32 WrT2[76 * 150];        // [pair p][j], f16x2-packed Wr^T
  __shared__ u32 aq2[cLQ * AQS];        // [l][jp] f16x2 pairs of aq (zero-pad)
  __shared__ float gl[cG];
  __shared__ float sc[NPAD];            // pp_t + h@Wr^T (zero-padded)
  __shared__ float waS[NPAD];
  __shared__ float c[cH];
  __shared__ __align__(16) u32 h2s[80];
  __shared__ float loge[64];
  __shared__ __align__(16) u32 alpha2[28];

  // one-time loads ----------------------------------------------------------
  u32 w2[76]; float bk = 0.f;
  if (tid < cG){
    const float* wr = Whh + (size_t)tid * cH;
    #pragma unroll
    for (int p = 0; p < 75; p++){
      float2 wv = *(const float2*)&wr[2 * p];
      w2[p] = pack2(wv.x, wv.y);
    }
    w2[75] = 0;
    bk = bm[tid];
  }
  u32 q2[28];
  if (tid < cG){
    const u16* QWu = (const u16*)QW;
    #pragma unroll
    for (int p = 0; p < 25; p++){
      size_t i0 = ((size_t)(2 * p) * cB + b) * cG + tid;
      size_t i1 = ((size_t)(2 * p + 1) * cB + b) * cG + tid;
      q2[p] = (u32)QWu[i0] | ((u32)QWu[i1] << 16);
    }
    q2[25] = 0; q2[26] = 0; q2[27] = 0;
  }
  for (int idx = tid; idx < cLQ * AQS; idx += 640){
    int l = idx / AQS, jp = idx % AQS;
    u32 v = 0;
    if (jp < 75){
      const float* ap = aq + ((size_t)l * cB + b) * cH;
      v = pack2(ap[2 * jp], ap[2 * jp + 1]);
    }
    aq2[idx] = v;
  }
  for (int i = tid; i < NPAD; i += 640) waS[i] = (i < cH) ? wa[i] : 0.f;
  for (int idx = tid; idx < 76 * 150; idx += 640){
    int p = idx / 150, k2 = idx % 150;
    WrT2[idx] = (p < 75) ? pack2(Wr[(size_t)k2 * cH + 2 * p],
                                 Wr[(size_t)k2 * cH + 2 * p + 1]) : 0u;
  }
  if (tid < cH) c[tid] = 0.f;
  if (tid < 80) h2s[tid] = 0;
  if (tid >= cH && tid < NPAD) sc[tid] = 0.f;
  __syncthreads();

  // prologue prefetch for step 0
  f16 xaCurH = (f16)0.f, xaNxtH = (f16)0.f;
  float ppCur = 0.f, ppNxt = 0.f;
  {
    int t0 = dir ? (cLP - 1) : 0;
    if (tid < cG) xaCurH = XA[((size_t)t0 * cB + b) * cG + tid];
    if (tid < cH) ppCur = pp[((size_t)t0 * cB + b) * cH + tid];
  }

  for (int s = 0; s < cLP; s++){
    int tt = dir ? (cLP - 1 - s) : s;
    float mk = (tt < len) ? 1.f : 0.f;

    // prefetch step s+1 (consumed next iteration)
    {
      int sn = (s + 1 < cLP) ? s + 1 : s;
      int tn = dir ? (cLP - 1 - sn) : sn;
      if (tid < cG) xaNxtH = XA[((size_t)tn * cB + b) * cG + tid];
      if (tid < cH) ppNxt = pp[((size_t)tn * cB + b) * cH + tid];
    }

    // A: sc = h@Wr^T + pp[tt]   (150 threads, conflict-free WrT2 reads)
    if (tid < cH){
      float aA[4] = {}, aB[4] = {};
      #pragma unroll
      for (int i = 0; i < 19; i++){
        uint4 hq = *(const uint4*)&h2s[4 * i];
        aA[i & 3] = fdot2_(hq.x, WrT2[(4 * i + 0) * 150 + tid], aA[i & 3]);
        aA[i & 3] = fdot2_(hq.y, WrT2[(4 * i + 1) * 150 + tid], aA[i & 3]);
        aB[i & 3] = fdot2_(hq.z, WrT2[(4 * i + 2) * 150 + tid], aB[i & 3]);
        aB[i & 3] = fdot2_(hq.w, WrT2[(4 * i + 3) * 150 + tid], aB[i & 3]);
      }
      sc[tid] = ((aA[0] + aA[1]) + (aA[2] + aA[3]))
              + ((aB[0] + aB[1]) + (aB[2] + aB[3])) + ppCur;
    }
    __syncthreads();

    // B: attention logits; 8 lanes/l, 20-wide even-aligned j-chunks.
    //    tanh = 1-2r with r=1/(1+e^{2x}); softmax drops constants.
    if (tid < 400){
      int l = tid >> 3, q = tid & 7;
      const u32* arow = &aq2[l * AQS + q * 10];
      float part = 0.f;
      #pragma unroll
      for (int p = 0; p < 10; p++){
        int j = q * 20 + 2 * p;
        float2 av = unp2(arow[p]);
        float x0 = av.x + sc[j];
        float x1 = av.y + sc[j + 1];
        float r0 = rcp_(1.f + exp2_(2.88539008f * x0));
        float r1 = rcp_(1.f + exp2_(2.88539008f * x1));
        part += waS[j] * r0 + waS[j + 1] * r1;
      }
      part += __shfl_xor(part, 1);
      part += __shfl_xor(part, 2);
      part += __shfl_xor(part, 4);
      if (q == 0) loge[l] = part;
    }
    __syncthreads();

    // C: softmax over 50 on wave 0, f16-packed alpha pairs
    if (tid < 64){
      float lg = (tid < cLQ) ? (-2.f * loge[tid]) : -1e30f;
      float mx = lg;
      #pragma unroll
      for (int off = 32; off; off >>= 1) mx = fmaxf(mx, __shfl_xor(mx, off));
      float e = (tid < cLQ) ? exp2_((lg - mx) * 1.44269504f) : 0.f;
      float sum = e;
      #pragma unroll
      for (int off = 32; off; off >>= 1) sum += __shfl_xor(sum, off);
      float al = e * rcp_(sum);
      float alhi = __shfl_down(al, 1);
      if (tid < cLQ && !(tid & 1)) alpha2[tid >> 1] = pack2(al, alhi);
      if (tid >= 25 && tid < 28) alpha2[tid] = 0;
    }
    __syncthreads();

    // D: gl = b + h@Whh^T + mk*(XA + alpha@QW)   (600 threads, reg weights)
    if (tid < cG){
      float aA[4] = {}, aB[4] = {};
      #pragma unroll
      for (int i = 0; i < 19; i++){
        uint4 hq = *(const uint4*)&h2s[4 * i];
        aA[i & 3] = fdot2_(hq.x, w2[4 * i + 0], aA[i & 3]);
        aA[i & 3] = fdot2_(hq.y, w2[4 * i + 1], aA[i & 3]);
        aB[i & 3] = fdot2_(hq.z, w2[4 * i + 2], aB[i & 3]);
        aB[i & 3] = fdot2_(hq.w, w2[4 * i + 3], aB[i & 3]);
      }
      float qA = 0.f, qB = 0.f;
      #pragma unroll
      for (int i = 0; i < 7; i++){
        uint4 a4 = *(const uint4*)&alpha2[4 * i];
        qA = fdot2_(a4.x, q2[4 * i + 0], qA);
        qA = fdot2_(a4.y, q2[4 * i + 1], qA);
        qB = fdot2_(a4.z, q2[4 * i + 2], qB);
        qB = fdot2_(a4.w, q2[4 * i + 3], qB);
      }
      float acc = ((aA[0] + aA[1]) + (aA[2] + aA[3]))
                + ((aB[0] + aB[1]) + (aB[2] + aB[3]));
      gl[tid] = bk + acc + mk * ((float)xaCurH + (qA + qB));
    }
    __syncthreads();

    // E: LSTM cell; h2,c2 masked inside recurrence (ref semantics)
    if (tid < 75){
      float hv[2];
      #pragma unroll
      for (int z = 0; z < 2; z++){
        int u = 2 * tid + z;
        float ig = sigm(gl[u]);
        float fg = sigm(gl[cH + u]);
        float gg = tanh_(gl[2 * cH + u]);
        float og = sigm(gl[3 * cH + u]);
        float c2 = (fg * c[u] + ig * gg) * mk;
        float hh = og * tanh_(c2) * mk;
        c[u] = c2;
        hv[z] = hh;
      }
      h2s[tid] = pack2(hv[0], hv[1]);
      float2 st; st.x = hv[0]; st.y = hv[1];
      *(float2*)&Hr[((size_t)tt * cB + b) * (2 * cH) + dir * cH + 2 * tid] = st;
    }
    __syncthreads();

    xaCurH = xaNxtH;
    ppCur  = ppNxt;
  }
}

// ---------------------------------------------------------------------------
// Answer pointer: 32 WGs (one per batch), 2 sequential iterations.
// ---------------------------------------------------------------------------
__global__ __launch_bounds__(640)
void ptr_k(const float* __restrict__ am, const float* __restrict__ Hr,
           const float* __restrict__ Wa, const float* __restrict__ baa,
           const float* __restrict__ wb,
           const float* __restrict__ apWih, const float* __restrict__ apWhh,
             const float* __restrict__ apb, float* __restrict__ out)
{
  int b = blockIdx.x, tid = threadIdx.x;
  __shared__ float ha[cH], ca[cH], haWa[160], wbs[160];
  __shared__ float beta[cLP], wHr[2 * cH], gl[cG], red[20];
  if (tid < cH){ ha[tid] = 0.f; ca[tid] = 0.f; }
  if (tid < 160) wbs[tid] = (tid < cH) ? wb[tid] : 0.f;
  __syncthreads();

  for (int it = 0; it < 2; ++it){
    if (tid < cH){
      float acc = baa[tid];
      const float* wr = Wa + (size_t)tid * cH;
      for (int i = 0; i < cH; i++) acc += ha[i] * wr[i];
      haWa[tid] = acc;
    } else if (tid < 160) haWa[tid] = 0.f;
    __syncthreads();

    {
      int tt = tid >> 4;
      int jq = tid & 15;
      for (int t0 = 0; t0 < cLP; t0 += 40){
        int t = t0 + tt;
        float part = 0.f;
        const float* amr = am + ((size_t)t * cB + b) * cH;
        #pragma unroll
        for (int i = 0; i < 10; i++){
          int j = jq * 10 + i;
          if (j < cH){
            float F = tanh_(amr[j] + haWa[j]);
            part += wbs[j] * F;
          }
        }
        part += __shfl_xor(part, 1);
        part += __shfl_xor(part, 2);
        part += __shfl_xor(part, 4);
        part += __shfl_xor(part, 8);
        if (jq == 0) beta[t] = part;
      }
    }
    __syncthreads();

    float x = (tid < cLP) ? beta[tid] : -1e30f;
    float mx = x;
    #pragma unroll
    for (int off = 32; off; off >>= 1) mx = fmaxf(mx, __shfl_xor(mx, off));
    if ((tid & 63) == 0) red[tid >> 6] = mx;
    __syncthreads();
    if (tid == 0){
      float m2 = red[0];
      for (int w = 1; w < 10; w++) m2 = fmaxf(m2, red[w]);
      red[16] = m2;
    }
    __syncthreads();
    mx = red[16];
    float e = (tid < cLP) ? exp2_((x - mx) * 1.44269504f) : 0.f;
    float sm = e;
    #pragma unroll
    for (int off = 32; off; off >>= 1) sm += __shfl_xor(sm, off);
    if ((tid & 63) == 0) red[tid >> 6] = sm;
    __syncthreads();
    if (tid == 0){
      float s2 = 0.f;
      for (int w = 0; w < 10; w++) s2 += red[w];
      red[17] = s2;
    }
    __syncthreads();
    float bsum = red[17];
    if (tid < cLP){
      float bt = e * rcp_(bsum);
      beta[tid] = bt;
      out[(size_t)it * cLP * cB + (size_t)tid * cB + b] = bt;
    }
    __syncthreads();

    if (tid < 2 * cH){
      float acc = 0.f;
      for (int t = 0; t < cLP; t++)
        acc += beta[t] * Hr[((size_t)t * cB + b) * (2 * cH) + tid];
      wHr[tid] = acc;
    }
    __syncthreads();

    if (tid < cG){
      float acc = apb[tid];
      const float* r1 = apWih + (size_t)tid * (2 * cH);
      for (int i = 0; i < 2 * cH; i++) acc += wHr[i] * r1[i];
      const float* r2 = apWhh + (size_t)tid * cH;
      for (int i = 0; i < cH; i++) acc += ha[i] * r2[i];
      gl[tid] = acc;
    }
    __syncthreads();
    if (tid < cH){
      float ig = sigm(gl[tid]);
      float fg = sigm(gl[cH + tid]);
      float gg = tanh_(gl[2 * cH + tid]);
      float og = sigm(gl[3 * cH + tid]);
      float c2 = fg * ca[tid] + ig * gg;
      ca[tid] = c2;
      ha[tid] = og * tanh_(c2);
    }
    __syncthreads();
  }
}

// ---------------------------------------------------------------------------
extern "C" void kernel_launch(void* const* d_in, const int* in_sizes, int n_in,
                              void* d_out, int out_size, void* d_ws, size_t ws_size,
                              hipStream_t stream)
{
  (void)in_sizes; (void)n_in; (void)out_size; (void)ws_size;
  const int*   p_ids = (const int*)d_in[0];
  const int*   q_ids = (const int*)d_in[1];
  const int*   plens = (const int*)d_in[2];
  const int*   qlens = (const int*)d_in[3];
  const float* emb   = (const float*)d_in[4];
  const float* pWih  = (const float*)d_in[5];
  const float* pWhh  = (const float*)d_in[6];
  const float* pb    = (const float*)d_in[7];
  const float* Wq    = (const float*)d_in[8];
  const float* Wp    = (const float*)d_in[9];
  const float* bp    = (const float*)d_in[10];
  const float* Wr    = (const float*)d_in[11];
  const float* wa    = (const float*)d_in[12];
  const float* mfWih = (const float*)d_in[14];
  const float* mfWhh = (const float*)d_in[15];
  const float* mfb   = (const float*)d_in[16];
  const float* mbWih = (const float*)d_in[17];
  const float* mbWhh = (const float*)d_in[18];
  const float* mbb   = (const float*)d_in[19];
  const float* Vm    = (const float*)d_in[20];
  const float* Waa   = (const float*)d_in[21];
  const float* baa   = (const float*)d_in[22];
  const float* wb    = (const float*)d_in[23];
  const float* apWih = (const float*)d_in[25];
  const float* apWhh = (const float*)d_in[26];
  const float* apb   = (const float*)d_in[27];
  float* out = (float*)d_out;

  // workspace layout (floats); total 22,560,000 f = 90.24 MB
  float* ws  = (float*)d_ws;
  float* XGp = ws;                       // [400*32][600] f32 (later aliased XAf)
  float* XGq = ws + 7680000;             // [50*32][600]  f32 (later aliased QW)
  f16*   XAb = (f16*)(ws + 8640000);     // [400*32][600] f16
  float* Hp  = ws + 12480000;            // [400*32][150]
  float* Hq  = ws + 14400000;            // [50*32][150]
  float* aqb = ws + 14640000;            // [50*32][150]
  float* ppb = ws + 14880000;            // [400*32][150]
  float* Hr  = ws + 16800000;            // [400*32][300]
  float* am  = ws + 20640000;            // [400*32][150]
  f16*   XAf = (f16*)XGp;                // alias: XGp dead after enc_k
  f16*   QWf = (f16*)XGq;                // alias: XGq dead after enc_k
  f16*   QWb = QWf + (size_t)1600 * 600;

  dim3 blk(256);
  gemm_k<<<dim3(10,200), blk, 0, stream>>>(nullptr, p_ids, emb, pWih, 300, pb,
                                           XGp, nullptr, 12800, 600, 300);
  gemm_k<<<dim3(10, 25), blk, 0, stream>>>(nullptr, q_ids, emb, pWih, 300, pb,
                                           XGq, nullptr, 1600, 600, 300);
  enc_k<<<64, 640, 0, stream>>>(XGp, XGq, pWhh, plens, qlens, Hp, Hq);
  gemm_k<<<dim3(3,200), blk, 0, stream>>>(Hp, nullptr, nullptr, Wp, 150, bp,
                                          ppb, nullptr, 12800, 150, 150);
  gemm_k<<<dim3(3, 25), blk, 0, stream>>>(Hq, nullptr, nullptr, Wq, 150, nullptr,
                                          aqb, nullptr, 1600, 150, 150);
  gemm_k<<<dim3(10,200), blk, 0, stream>>>(Hp, nullptr, nullptr, mfWih, 300, nullptr,
                                           nullptr, XAf, 12800, 600, 150);
  gemm_k<<<dim3(10,200), blk, 0, stream>>>(Hp, nullptr, nullptr, mbWih, 300, nullptr,
                                           nullptr, XAb, 12800, 600, 150);
  gemm_k<<<dim3(10, 25), blk, 0, stream>>>(Hq, nullptr, nullptr, mfWih + 150, 300, nullptr,
                                           nullptr, QWf, 1600, 600, 150);
  gemm_k<<<dim3(10, 25), blk, 0, stream>>>(Hq, nullptr, nullptr, mbWih + 150, 300, nullptr,
                                           nullptr, QWb, 1600, 600, 150);
  match_k<<<64, 640, 0, stream>>>(XAf, XAb, QWf, QWb, aqb, ppb, mfWhh, mbWhh,
                                  mfb, mbb, Wr, wa, plens, Hr);
  gemm_k<<<dim3(3,200), blk, 0, stream>>>(Hr, nullptr, nullptr, Vm, 300, nullptr,
                                          am, nullptr, 12800, 150, 300);
  ptr_k<<<32, 640, 0, stream>>>(am, Hr, Waa, baa, wb, apWih, apWhh, apb, out);
}

// Round 4
// 2551.501 us; speedup vs baseline: 1.9533x; 1.1821x over previous
//
#include <hip/hip_runtime.h>

// MatchLSTM forward pipeline for MI355X.
// R4: force recurrent weights into VGPRs with NAMED uint4 variables (macro
// repetition) — array allocas were staying in scratch (VGPR_Count=84 < 104
// array words), costing ~1.9us/step of L2 spill streaming in match_k/enc_k.

typedef _Float16 f16;
typedef f16 f16x2 __attribute__((ext_vector_type(2)));
typedef unsigned int u32;
typedef unsigned short u16;

constexpr int cLP = 400, cLQ = 50, cB = 32, cH = 150, cG = 600;

__device__ __forceinline__ float exp2_(float x){
#if __has_builtin(__builtin_amdgcn_exp2f)
  return __builtin_amdgcn_exp2f(x);
#else
  return exp2f(x);
#endif
}
__device__ __forceinline__ float rcp_(float x){
#if __has_builtin(__builtin_amdgcn_rcpf)
  return __builtin_amdgcn_rcpf(x);
#else
  return 1.0f / x;
#endif
}
__device__ __forceinline__ float sigm(float x){ return rcp_(1.f + exp2_(-1.44269504f * x)); }
__device__ __forceinline__ float tanh_(float x){ return 1.f - 2.f * rcp_(1.f + exp2_(2.88539008f * x)); }

union U2 { u32 u; f16x2 h; };

__device__ __forceinline__ float fdot2_(u32 a, u32 b, float c){
  U2 ua, ub; ua.u = a; ub.u = b;
#if __has_builtin(__builtin_amdgcn_fdot2)
  return __builtin_amdgcn_fdot2(ua.h, ub.h, c, false);
#else
  return c + (float)ua.h[0] * (float)ub.h[0] + (float)ua.h[1] * (float)ub.h[1];
#endif
}
__device__ __forceinline__ u32 pack2(float x, float y){
  U2 p; p.h[0] = (f16)x; p.h[1] = (f16)y; return p.u;
}
__device__ __forceinline__ float2 unp2(u32 v){
  U2 p; p.u = v; return make_float2((float)p.h[0], (float)p.h[1]);
}

// load 4 f16x2 pairs (8 floats) from a weight row at pair offset 4*i
__device__ __forceinline__ uint4 ldw4(const float* __restrict__ wr, int i){
  uint4 r;
  r.x = pack2(wr[8*i+0], wr[8*i+1]);
  r.y = pack2(wr[8*i+2], wr[8*i+3]);
  r.z = pack2(wr[8*i+4], wr[8*i+5]);
  r.w = pack2(wr[8*i+6], wr[8*i+7]);
  return r;
}

#define REP19(M) M(0) M(1) M(2) M(3) M(4) M(5) M(6) M(7) M(8) M(9) \
                 M(10) M(11) M(12) M(13) M(14) M(15) M(16) M(17) M(18)
#define REP7(M) M(0) M(1) M(2) M(3) M(4) M(5) M(6)

// ---------------------------------------------------------------------------
// Generic f32 GEMM: C[M][N] = A[M][K] @ W[N][K]^T (+bias). Optional embedding
// gather for A rows. Optional f16 output. Tile 64x64, 4x4/thread, 256 thr.
// ---------------------------------------------------------------------------
__global__ __launch_bounds__(256)
void gemm_k(const float* __restrict__ A, const int* __restrict__ ids,
            const float* __restrict__ emb,
            const float* __restrict__ W, int ldw, const float* __restrict__ bias,
            float* __restrict__ Cf, f16* __restrict__ Ch,
            int M, int N, int K)
{
  __shared__ __align__(16) float As[16][68];
  __shared__ __align__(16) float Wt[16][68];
  __shared__ int sids[64];
  int tid = threadIdx.x;
  int n0 = blockIdx.x * 64;
  int m0 = blockIdx.y * 64;
  int tx = tid & 15, ty = tid >> 4;
  if (ids){ if (tid < 64) sids[tid] = ids[m0 + tid]; }
  __syncthreads();

  float acc[4][4] = {};
  int sm = tid >> 2;
  int kq = (tid & 3) << 2;
  const float* arow = ids ? (emb + (size_t)sids[sm] * K)
                          : (A   + (size_t)(m0 + sm) * K);
  const float* wrow = W + (size_t)(n0 + sm) * ldw;
  bool nok = (n0 + sm) < N;

  for (int k0 = 0; k0 < K; k0 += 16){
    #pragma unroll
    for (int p = 0; p < 4; p++){
      int kk = kq + p, k = k0 + kk;
      As[kk][sm] = (k < K) ? arow[k] : 0.f;
      Wt[kk][sm] = (nok && k < K) ? wrow[k] : 0.f;
    }
    __syncthreads();
    #pragma unroll
    for (int kk = 0; kk < 16; kk++){
      float4 av = *(const float4*)&As[kk][ty << 2];
      float4 wv = *(const float4*)&Wt[kk][tx << 2];
      float a[4] = {av.x, av.y, av.z, av.w};
      float w[4] = {wv.x, wv.y, wv.z, wv.w};
      #pragma unroll
      for (int i = 0; i < 4; i++)
        #pragma unroll
        for (int j = 0; j < 4; j++)
          acc[i][j] += a[i] * w[j];
    }
    __syncthreads();
  }
  float bj[4];
  #pragma unroll
  for (int j = 0; j < 4; j++){
    int n = n0 + (tx << 2) + j;
    bj[j] = (bias && n < N) ? bias[n] : 0.f;
  }
  #pragma unroll
  for (int i = 0; i < 4; i++){
    int m = m0 + (ty << 2) + i;
    #pragma unroll
    for (int j = 0; j < 4; j++){
      int n = n0 + (tx << 2) + j;
      if (n < N){
        size_t ci = (size_t)m * N + n;
        float v = acc[i][j] + bj[j];
        if (Ch) Ch[ci] = (f16)v; else Cf[ci] = v;
      }
    }
  }
}

// ---------------------------------------------------------------------------
// Encoder LSTM. 64 WGs: wg<32 -> passage b, else question b. 640 threads.
// Whh rows in NAMED uint4 VGPRs (19 per thread). XG prefetched 1 step ahead.
// ---------------------------------------------------------------------------
__global__ __launch_bounds__(640, 3)
void enc_k(const float* __restrict__ XGp, const float* __restrict__ XGq,
           const float* __restrict__ Whh,
           const int* __restrict__ plens, const int* __restrict__ qlens,
           float* __restrict__ Hp, float* __restrict__ Hq)
{
  int wg = blockIdx.x;
  bool isq = wg >= cB;
  int b = wg & (cB - 1);
  const float* XG = isq ? XGq : XGp;
  float* Hout = isq ? Hq : Hp;
  int T   = isq ? cLQ : cLP;
  int len = (isq ? qlens : plens)[b];
  int tid = threadIdx.x;

  __shared__ float c[cH], gl[cG];
  __shared__ __align__(16) u32 h2s[80];

#define DECLW(i) uint4 w##i;
  REP19(DECLW)
#undef DECLW
  {
    const float* wr = Whh + (size_t)(tid < cG ? tid : 0) * cH;
#define LOADW(i) w##i = ldw4(wr, i);
    REP19(LOADW)
#undef LOADW
    w18.z = pack2(wr[148], wr[149]);   // redo pairs 74,75 without OOB
    w18.w = 0;
  }
  if (tid < cH) c[tid] = 0.f;
  if (tid < 80) h2s[tid] = 0;
  __syncthreads();

  float xgCur = 0.f;
  if (tid < cG) xgCur = XG[(size_t)b * cG + tid];

  for (int t = 0; t < T; t++){
    int tn = (t + 1 < T) ? t + 1 : t;
    float xgN = 0.f;
    if (tid < cG) xgN = XG[((size_t)tn * cB + b) * cG + tid];

    if (tid < cG){
      float aA = 0.f, aB = 0.f, aC = 0.f, aD = 0.f;
#define DOTW(i) { uint4 hq = *(const uint4*)&h2s[4*(i)]; \
      aA = fdot2_(hq.x, w##i.x, aA); aB = fdot2_(hq.y, w##i.y, aB); \
      aC = fdot2_(hq.z, w##i.z, aC); aD = fdot2_(hq.w, w##i.w, aD); }
      REP19(DOTW)
#undef DOTW
      gl[tid] = xgCur + ((aA + aB) + (aC + aD));
    }
    __syncthreads();
    if (tid < 75){
      float hv[2];
      #pragma unroll
      for (int z = 0; z < 2; z++){
        int u = 2 * tid + z;
        float ig = sigm(gl[u]);
        float fg = sigm(gl[cH + u]);
        float gg = tanh_(gl[2 * cH + u]);
        float og = sigm(gl[3 * cH + u]);
        float c2 = fg * c[u] + ig * gg;
        float hh = og * tanh_(c2);
        c[u] = c2;
        hv[z] = hh;
      }
      h2s[tid] = pack2(hv[0], hv[1]);      // unmasked h carries the recurrence
      float mk = (t < len) ? 1.f : 0.f;
      float2 st; st.x = hv[0] * mk; st.y = hv[1] * mk;
      *(float2*)&Hout[((size_t)t * cB + b) * cH + 2 * tid] = st;
    }
    __syncthreads();
    xgCur = xgN;
  }
}

// ---------------------------------------------------------------------------
// Match-LSTM, fwd + bwd. 64 WGs = dir(2) x batch(32), 640 threads.
// 5-phase structure; Whh (19 uint4) and QW (7 uint4) in NAMED registers;
// aq + wa in LDS; XA/pp prefetched one step ahead.
// ---------------------------------------------------------------------------
__global__ __launch_bounds__(640, 3)
void match_k(const f16* __restrict__ XAf, const f16* __restrict__ XAb,
             const f16* __restrict__ QWf, const f16* __restrict__ QWb,
             const float* __restrict__ aq, const float* __restrict__ pp,
             const float* __restrict__ mfWhh, const float* __restrict__ mbWhh,
             const float* __restrict__ mfb, const float* __restrict__ mbb,
             const float* __restrict__ Wr, const float* __restrict__ wa,
             const int* __restrict__ plens, float* __restrict__ Hr)
{
  constexpr int NPAD = 160;
  constexpr int AQS  = 81;
  int wg = blockIdx.x;
  int dir = wg >> 5;
  int b = wg & 31;
  const f16* XA = dir ? XAb : XAf;
  const f16* QW = dir ? QWb : QWf;
  const float* Whh = dir ? mbWhh : mfWhh;
  const float* bm  = dir ? mbb   : mfb;
  int len = plens[b];
  int tid = threadIdx.x;

  __shared__ u32 WrT2[76 * 150];        // [pair p][j], f16x2-packed Wr^T
  __shared__ u32 aq2[cLQ * AQS];        // [l][jp] f16x2 pairs of aq (zero-pad)
  __shared__ float gl[cG];
  __shared__ float sc[NPAD];            // pp_t + h@Wr^T (zero-padded)
  __shared__ float waS[NPAD];
  __shared__ float c[cH];
  __shared__ __align__(16) u32 h2s[80];
  __shared__ float loge[64];
  __shared__ __align__(16) u32 alpha2[28];

  // ---- one-time loads: weights into NAMED registers ----
#define DECLW(i) uint4 w##i;
  REP19(DECLW)
#undef DECLW
  float bk = 0.f;
  {
    const float* wr = Whh + (size_t)(tid < cG ? tid : 0) * cH;
#define LOADW(i) w##i = ldw4(wr, i);
    REP19(LOADW)
#undef LOADW
    w18.z = pack2(wr[148], wr[149]);
    w18.w = 0;
    if (tid < cG) bk = bm[tid];
  }
#define DECLQ(i) uint4 q##i;
  REP7(DECLQ)
#undef DECLQ
  {
    const u16* QWu = (const u16*)QW;
    int row = (tid < cG) ? tid : 0;
    // pair p holds (alpha_{2p}, alpha_{2p+1}) weights: QW[l][b][row]
#define QP(p) ((u32)QWu[((size_t)(2*(p)) * cB + b) * cG + row] | \
               ((u32)QWu[((size_t)(2*(p)+1) * cB + b) * cG + row] << 16))
#define LOADQ(i) q##i.x = QP(4*(i)+0); q##i.y = QP(4*(i)+1); \
                 q##i.z = QP(4*(i)+2); q##i.w = QP(4*(i)+3);
    LOADQ(0) LOADQ(1) LOADQ(2) LOADQ(3) LOADQ(4) LOADQ(5)
    q6.x = QP(24); q6.y = 0; q6.z = 0; q6.w = 0;
#undef LOADQ
#undef QP
  }
  for (int idx = tid; idx < cLQ * AQS; idx += 640){
    int l = idx / AQS, jp = idx % AQS;
    u32 v = 0;
    if (jp < 75){
      const float* ap = aq + ((size_t)l * cB + b) * cH;
      v = pack2(ap[2 * jp], ap[2 * jp + 1]);
    }
    aq2[idx] = v;
  }
  for (int i = tid; i < NPAD; i += 640) waS[i] = (i < cH) ? wa[i] : 0.f;
  for (int idx = tid; idx < 76 * 150; idx += 640){
    int p = idx / 150, k2 = idx % 150;
    WrT2[idx] = (p < 75) ? pack2(Wr[(size_t)k2 * cH + 2 * p],
                                 Wr[(size_t)k2 * cH + 2 * p + 1]) : 0u;
  }
  if (tid < cH) c[tid] = 0.f;
  if (tid < 80) h2s[tid] = 0;
  if (tid >= cH && tid < NPAD) sc[tid] = 0.f;
  __syncthreads();

  // prologue prefetch for step 0
  f16 xaCurH = (f16)0.f, xaNxtH = (f16)0.f;
  float ppCur = 0.f, ppNxt = 0.f;
  {
    int t0 = dir ? (cLP - 1) : 0;
    if (tid < cG) xaCurH = XA[((size_t)t0 * cB + b) * cG + tid];
    if (tid < cH) ppCur = pp[((size_t)t0 * cB + b) * cH + tid];
  }

  for (int s = 0; s < cLP; s++){
    int tt = dir ? (cLP - 1 - s) : s;
    float mk = (tt < len) ? 1.f : 0.f;

    // prefetch step s+1 (consumed next iteration)
    {
      int sn = (s + 1 < cLP) ? s + 1 : s;
      int tn = dir ? (cLP - 1 - sn) : sn;
      if (tid < cG) xaNxtH = XA[((size_t)tn * cB + b) * cG + tid];
      if (tid < cH) ppNxt = pp[((size_t)tn * cB + b) * cH + tid];
    }

    // A: sc = h@Wr^T + pp[tt]   (150 threads, conflict-free WrT2 reads)
    if (tid < cH){
      float sA = 0.f, sB = 0.f, sC = 0.f, sD = 0.f;
#define DOTA(i) { uint4 hq = *(const uint4*)&h2s[4*(i)]; \
      sA = fdot2_(hq.x, WrT2[(4*(i)+0)*150 + tid], sA); \
      sB = fdot2_(hq.y, WrT2[(4*(i)+1)*150 + tid], sB); \
      sC = fdot2_(hq.z, WrT2[(4*(i)+2)*150 + tid], sC); \
      sD = fdot2_(hq.w, WrT2[(4*(i)+3)*150 + tid], sD); }
      REP19(DOTA)
#undef DOTA
      sc[tid] = ((sA + sB) + (sC + sD)) + ppCur;
    }
    __syncthreads();

    // B: attention logits; 8 lanes/l, 20-wide even-aligned j-chunks.
    if (tid < 400){
      int l = tid >> 3, q = tid & 7;
      const u32* arow = &aq2[l * AQS + q * 10];
      float part = 0.f;
      #pragma unroll
      for (int p = 0; p < 10; p++){
        int j = q * 20 + 2 * p;
        float2 av = unp2(arow[p]);
        float x0 = av.x + sc[j];
        float x1 = av.y + sc[j + 1];
        float r0 = rcp_(1.f + exp2_(2.88539008f * x0));
        float r1 = rcp_(1.f + exp2_(2.88539008f * x1));
        part += waS[j] * r0 + waS[j + 1] * r1;
      }
      part += __shfl_xor(part, 1);
      part += __shfl_xor(part, 2);
      part += __shfl_xor(part, 4);
      if (q == 0) loge[l] = part;
    }
    __syncthreads();

    // C: softmax over 50 on wave 0, f16-packed alpha pairs
    if (tid < 64){
      float lg = (tid < cLQ) ? (-2.f * loge[tid]) : -1e30f;
      float mx = lg;
      #pragma unroll
      for (int off = 32; off; off >>= 1) mx = fmaxf(mx, __shfl_xor(mx, off));
      float e = (tid < cLQ) ? exp2_((lg - mx) * 1.44269504f) : 0.f;
      float sum = e;
      #pragma unroll
      for (int off = 32; off; off >>= 1) sum += __shfl_xor(sum, off);
      float al = e * rcp_(sum);
      float alhi = __shfl_down(al, 1);
      if (tid < cLQ && !(tid & 1)) alpha2[tid >> 1] = pack2(al, alhi);
      if (tid >= 25 && tid < 28) alpha2[tid] = 0;
    }
    __syncthreads();

    // D: gl = b + h@Whh^T + mk*(XA + alpha@QW)   (600 threads, reg weights)
    if (tid < cG){
      float aA = 0.f, aB = 0.f, aC = 0.f, aD = 0.f;
#define DOTW(i) { uint4 hq = *(const uint4*)&h2s[4*(i)]; \
      aA = fdot2_(hq.x, w##i.x, aA); aB = fdot2_(hq.y, w##i.y, aB); \
      aC = fdot2_(hq.z, w##i.z, aC); aD = fdot2_(hq.w, w##i.w, aD); }
      REP19(DOTW)
#undef DOTW
      float qA = 0.f, qB = 0.f;
#define DOTQ(i) { uint4 a4 = *(const uint4*)&alpha2[4*(i)]; \
      qA = fdot2_(a4.x, q##i.x, qA); qB = fdot2_(a4.y, q##i.y, qB); \
      qA = fdot2_(a4.z, q##i.z, qA); qB = fdot2_(a4.w, q##i.w, qB); }
      REP7(DOTQ)
#undef DOTQ
      float acc = ((aA + aB) + (aC + aD));
      gl[tid] = bk + acc + mk * ((float)xaCurH + (qA + qB));
    }
    __syncthreads();

    // E: LSTM cell; h2,c2 masked inside recurrence (ref semantics)
    if (tid < 75){
      float hv[2];
      #pragma unroll
      for (int z = 0; z < 2; z++){
        int u = 2 * tid + z;
        float ig = sigm(gl[u]);
        float fg = sigm(gl[cH + u]);
        float gg = tanh_(gl[2 * cH + u]);
        float og = sigm(gl[3 * cH + u]);
        float c2 = (fg * c[u] + ig * gg) * mk;
        float hh = og * tanh_(c2) * mk;
        c[u] = c2;
        hv[z] = hh;
      }
      h2s[tid] = pack2(hv[0], hv[1]);
      float2 st; st.x = hv[0]; st.y = hv[1];
      *(float2*)&Hr[((size_t)tt * cB + b) * (2 * cH) + dir * cH + 2 * tid] = st;
    }
    __syncthreads();

    xaCurH = xaNxtH;
    ppCur  = ppNxt;
  }
}

// ---------------------------------------------------------------------------
// Answer pointer: 32 WGs (one per batch), 2 sequential iterations.
// ---------------------------------------------------------------------------
__global__ __launch_bounds__(640)
void ptr_k(const float* __restrict__ am, const float* __restrict__ Hr,
           const float* __restrict__ Wa, const float* __restrict__ baa,
           const float* __restrict__ wb,
           const float* __restrict__ apWih, const float* __restrict__ apWhh,
             const float* __restrict__ apb, float* __restrict__ out)
{
  int b = blockIdx.x, tid = threadIdx.x;
  __shared__ float ha[cH], ca[cH], haWa[160], wbs[160];
  __shared__ float beta[cLP], wHr[2 * cH], gl[cG], red[20];
  if (tid < cH){ ha[tid] = 0.f; ca[tid] = 0.f; }
  if (tid < 160) wbs[tid] = (tid < cH) ? wb[tid] : 0.f;
  __syncthreads();

  for (int it = 0; it < 2; ++it){
    if (tid < cH){
      float acc = baa[tid];
      const float* wr = Wa + (size_t)tid * cH;
      for (int i = 0; i < cH; i++) acc += ha[i] * wr[i];
      haWa[tid] = acc;
    } else if (tid < 160) haWa[tid] = 0.f;
    __syncthreads();

    {
      int tt = tid >> 4;
      int jq = tid & 15;
      for (int t0 = 0; t0 < cLP; t0 += 40){
        int t = t0 + tt;
        float part = 0.f;
        const float* amr = am + ((size_t)t * cB + b) * cH;
        #pragma unroll
        for (int i = 0; i < 10; i++){
          int j = jq * 10 + i;
          if (j < cH){
            float F = tanh_(amr[j] + haWa[j]);
            part += wbs[j] * F;
          }
        }
        part += __shfl_xor(part, 1);
        part += __shfl_xor(part, 2);
        part += __shfl_xor(part, 4);
        part += __shfl_xor(part, 8);
        if (jq == 0) beta[t] = part;
      }
    }
    __syncthreads();

    float x = (tid < cLP) ? beta[tid] : -1e30f;
    float mx = x;
    #pragma unroll
    for (int off = 32; off; off >>= 1) mx = fmaxf(mx, __shfl_xor(mx, off));
    if ((tid & 63) == 0) red[tid >> 6] = mx;
    __syncthreads();
    if (tid == 0){
      float m2 = red[0];
      for (int w = 1; w < 10; w++) m2 = fmaxf(m2, red[w]);
      red[16] = m2;
    }
    __syncthreads();
    mx = red[16];
    float e = (tid < cLP) ? exp2_((x - mx) * 1.44269504f) : 0.f;
    float sm = e;
    #pragma unroll
    for (int off = 32; off; off >>= 1) sm += __shfl_xor(sm, off);
    if ((tid & 63) == 0) red[tid >> 6] = sm;
    __syncthreads();
    if (tid == 0){
      float s2 = 0.f;
      for (int w = 0; w < 10; w++) s2 += red[w];
      red[17] = s2;
    }
    __syncthreads();
    float bsum = red[17];
    if (tid < cLP){
      float bt = e * rcp_(bsum);
      beta[tid] = bt;
      out[(size_t)it * cLP * cB + (size_t)tid * cB + b] = bt;
    }
    __syncthreads();

    if (tid < 2 * cH){
      float acc = 0.f;
      for (int t = 0; t < cLP; t++)
        acc += beta[t] * Hr[((size_t)t * cB + b) * (2 * cH) + tid];
      wHr[tid] = acc;
    }
    __syncthreads();

    if (tid < cG){
      float acc = apb[tid];
      const float* r1 = apWih + (size_t)tid * (2 * cH);
      for (int i = 0; i < 2 * cH; i++) acc += wHr[i] * r1[i];
      const float* r2 = apWhh + (size_t)tid * cH;
      for (int i = 0; i < cH; i++) acc += ha[i] * r2[i];
      gl[tid] = acc;
    }
    __syncthreads();
    if (tid < cH){
      float ig = sigm(gl[tid]);
      float fg = sigm(gl[cH + tid]);
      float gg = tanh_(gl[2 * cH + tid]);
      float og = sigm(gl[3 * cH + tid]);
      float c2 = fg * ca[tid] + ig * gg;
      ca[tid] = c2;
      ha[tid] = og * tanh_(c2);
    }
    __syncthreads();
  }
}

// ---------------------------------------------------------------------------
extern "C" void kernel_launch(void* const* d_in, const int* in_sizes, int n_in,
                              void* d_out, int out_size, void* d_ws, size_t ws_size,
                              hipStream_t stream)
{
  (void)in_sizes; (void)n_in; (void)out_size; (void)ws_size;
  const int*   p_ids = (const int*)d_in[0];
  const int*   q_ids = (const int*)d_in[1];
  const int*   plens = (const int*)d_in[2];
  const int*   qlens = (const int*)d_in[3];
  const float* emb   = (const float*)d_in[4];
  const float* pWih  = (const float*)d_in[5];
  const float* pWhh  = (const float*)d_in[6];
  const float* pb    = (const float*)d_in[7];
  const float* Wq    = (const float*)d_in[8];
  const float* Wp    = (const float*)d_in[9];
  const float* bp    = (const float*)d_in[10];
  const float* Wr    = (const float*)d_in[11];
  const float* wa    = (const float*)d_in[12];
  const float* mfWih = (const float*)d_in[14];
  const float* mfWhh = (const float*)d_in[15];
  const float* mfb   = (const float*)d_in[16];
  const float* mbWih = (const float*)d_in[17];
  const float* mbWhh = (const float*)d_in[18];
  const float* mbb   = (const float*)d_in[19];
  const float* Vm    = (const float*)d_in[20];
  const float* Waa   = (const float*)d_in[21];
  const float* baa   = (const float*)d_in[22];
  const float* wb    = (const float*)d_in[23];
  const float* apWih = (const float*)d_in[25];
  const float* apWhh = (const float*)d_in[26];
  const float* apb   = (const float*)d_in[27];
  float* out = (float*)d_out;

  // workspace layout (floats); total 22,560,000 f = 90.24 MB
  float* ws  = (float*)d_ws;
  float* XGp = ws;                       // [400*32][600] f32 (later aliased XAf)
  float* XGq = ws + 7680000;             // [50*32][600]  f32 (later aliased QW)
  f16*   XAb = (f16*)(ws + 8640000);     // [400*32][600] f16
  float* Hp  = ws + 12480000;            // [400*32][150]
  float* Hq  = ws + 14400000;            // [50*32][150]
  float* aqb = ws + 14640000;            // [50*32][150]
  float* ppb = ws + 14880000;            // [400*32][150]
  float* Hr  = ws + 16800000;            // [400*32][300]
  float* am  = ws + 20640000;            // [400*32][150]
  f16*   XAf = (f16*)XGp;                // alias: XGp dead after enc_k
  f16*   QWf = (f16*)XGq;                // alias: XGq dead after enc_k
  f16*   QWb = QWf + (size_t)1600 * 600;

  dim3 blk(256);
  gemm_k<<<dim3(10,200), blk, 0, stream>>>(nullptr, p_ids, emb, pWih, 300, pb,
                                           XGp, nullptr, 12800, 600, 300);
  gemm_k<<<dim3(10, 25), blk, 0, stream>>>(nullptr, q_ids, emb, pWih, 300, pb,
                                           XGq, nullptr, 1600, 600, 300);
  enc_k<<<64, 640, 0, stream>>>(XGp, XGq, pWhh, plens, qlens, Hp, Hq);
  gemm_k<<<dim3(3,200), blk, 0, stream>>>(Hp, nullptr, nullptr, Wp, 150, bp,
                                          ppb, nullptr, 12800, 150, 150);
  gemm_k<<<dim3(3, 25), blk, 0, stream>>>(Hq, nullptr, nullptr, Wq, 150, nullptr,
                                          aqb, nullptr, 1600, 150, 150);
  gemm_k<<<dim3(10,200), blk, 0, stream>>>(Hp, nullptr, nullptr, mfWih, 300, nullptr,
                                           nullptr, XAf, 12800, 600, 150);
  gemm_k<<<dim3(10,200), blk, 0, stream>>>(Hp, nullptr, nullptr, mbWih, 300, nullptr,
                                           nullptr, XAb, 12800, 600, 150);
  gemm_k<<<dim3(10, 25), blk, 0, stream>>>(Hq, nullptr, nullptr, mfWih + 150, 300, nullptr,
                                           nullptr, QWf, 1600, 600, 150);
  gemm_k<<<dim3(10, 25), blk, 0, stream>>>(Hq, nullptr, nullptr, mbWih + 150, 300, nullptr,
                                           nullptr, QWb, 1600, 600, 150);
  match_k<<<64, 640, 0, stream>>>(XAf, XAb, QWf, QWb, aqb, ppb, mfWhh, mbWhh,
                                  mfb, mbb, Wr, wa, plens, Hr);
  gemm_k<<<dim3(3,200), blk, 0, stream>>>(Hr, nullptr, nullptr, Vm, 300, nullptr,
                                          am, nullptr, 12800, 150, 300);
  ptr_k<<<32, 640, 0, stream>>>(am, Hr, Waa, baa, wb, apWih, apWhh, apb, out);
}